// Round 11
// baseline (43.580 us; speedup 1.0000x reference)
//
#include <hip/hip_runtime.h>
#include <hip/hip_bf16.h>

#define BATCH    512
#define IN_WIDTH 4096
#define OUT_F    4096
#define FAN_IN   128
#define BCHUNK   16                 // batches per LDS-resident slice
#define NBG      (BATCH / BCHUNK)   // 32
#define O_SPLIT  2048               // o<O_SPLIT: LDS leg; o>=O_SPLIT: L2 leg

typedef float    v2f __attribute__((ext_vector_type(2)));
typedef uint32_t v4u __attribute__((ext_vector_type(4)));

// ---------------------------------------------------------------------------
// Kernel A: input[b][j] f32 -> BOTH  inTg[b/16][j][16]  AND  inTf[j][512] bf16
// ---------------------------------------------------------------------------
__global__ __launch_bounds__(256) void k_transpose_in(const float* __restrict__ in,
                                                      uint16_t* __restrict__ inTg,
                                                      uint16_t* __restrict__ inTf) {
  __shared__ float tile[32][33];
  const int jt = blockIdx.x * 32;
  const int bt = blockIdx.y * 32;
  const int tx = threadIdx.x;       // 0..31
  const int ty = threadIdx.y;       // 0..7
#pragma unroll
  for (int r = 0; r < 32; r += 8) {
    tile[ty + r][tx] = in[(size_t)(bt + ty + r) * IN_WIDTH + (jt + tx)];
  }
  __syncthreads();
#pragma unroll
  for (int r = 0; r < 32; r += 8) {
    const int b = bt + tx;
    const int j = jt + ty + r;
    __hip_bfloat16 hv = __float2bfloat16(tile[tx][ty + r]);
    const uint16_t u = *reinterpret_cast<const uint16_t*>(&hv);
    inTg[((size_t)(b >> 4) * IN_WIDTH + j) * BCHUNK + (b & 15)] = u;
    inTf[(size_t)j * BATCH + b] = u;
  }
}

// ---------------------------------------------------------------------------
// Kernel P: pack idx+weight -> pk[o][f] = {j, bits(w)}  (LDS-leg o's only)
// ---------------------------------------------------------------------------
__global__ __launch_bounds__(256) void k_pack(const int* __restrict__ idx,
                                              const float* __restrict__ weight,
                                              uint2* __restrict__ pk) {
  const int i = blockIdx.x * 256 + threadIdx.x;
  uint2 e;
  e.x = (uint32_t)idx[i];
  e.y = __float_as_uint(weight[i]);
  pk[i] = e;
}

// consume one 16B chunk (8 bf16) into a0..a3 (in scope)
#define CONSUME(v, wbits)                                              \
  do {                                                                 \
    const float wf_ = __uint_as_float(wbits);                          \
    v2f w2_; w2_[0] = wf_; w2_[1] = wf_;                               \
    v2f x0_, x1_, x2_, x3_;                                            \
    x0_[0] = __uint_as_float((v)[0] << 16);                            \
    x0_[1] = __uint_as_float((v)[0] & 0xffff0000u);                    \
    x1_[0] = __uint_as_float((v)[1] << 16);                            \
    x1_[1] = __uint_as_float((v)[1] & 0xffff0000u);                    \
    x2_[0] = __uint_as_float((v)[2] << 16);                            \
    x2_[1] = __uint_as_float((v)[2] & 0xffff0000u);                    \
    x3_[0] = __uint_as_float((v)[3] << 16);                            \
    x3_[1] = __uint_as_float((v)[3] & 0xffff0000u);                    \
    a0 += x0_ * w2_; a1 += x1_ * w2_; a2 += x2_ * w2_; a3 += x3_ * w2_;\
  } while (0)

// ---------------------------------------------------------------------------
// Kernel B: dual-fabric gather. 1 block/CU (1024 thr, 128 KB LDS).
// Waves 0-7 : LDS leg (R7 pipeline) — o = og*256 + wv*32 + (l>>1), slice bg.
// Waves 8-15: L2 leg (R10 pipeline) — o = O_SPLIT + blk*8 + (wv-8), all b.
// The two legs exercise disjoint pipes (DS unit vs TA/TCP/L2) concurrently.
// ---------------------------------------------------------------------------
__global__ __launch_bounds__(1024, 1) void k_gather_hyb2(
    const uint16_t* __restrict__ inTg, const uint16_t* __restrict__ inTf,
    const uint2* __restrict__ pk, const int* __restrict__ idx,
    const float* __restrict__ weight, const float* __restrict__ bias,
    float* __restrict__ out, float* __restrict__ outT) {
  extern __shared__ char lds[];
  const int blk = blockIdx.x;
  const int og  = blk & 7;
  const int bg  = blk >> 3;
  const int t   = threadIdx.x;

  // ---- all waves stage the 128 KB bg-slice (contiguous) ----
  {
    const v4u* __restrict__ src =
        reinterpret_cast<const v4u*>(inTg + (size_t)bg * IN_WIDTH * BCHUNK);
    v4u* dst = reinterpret_cast<v4u*>(lds);
#pragma unroll
    for (int i = 0; i < 8; ++i) dst[i * 1024 + t] = src[i * 1024 + t];
  }
  __syncthreads();

  const int wv = t >> 6;
  const int l  = t & 63;

  v2f a0 = {0.f, 0.f}, a1 = {0.f, 0.f}, a2 = {0.f, 0.f}, a3 = {0.f, 0.f};

  if (wv < 8) {
    // =================== LDS leg (R7 pipeline) =============================
    const int p = l & 1;
    const int o = og * 256 + wv * 32 + (l >> 1);
    const uint32_t sb = (uint32_t)(size_t)lds + (uint32_t)(p * 16);
    const uint4* __restrict__ pko =
        reinterpret_cast<const uint4*>(pk + (size_t)o * FAN_IN);

#define DSREAD(d, jj) \
  asm volatile("ds_read_b128 %0, %1" : "=v"(d) : "v"(sb + ((jj) << 5)))
#define WAIT4() do { asm volatile("s_waitcnt lgkmcnt(4)" ::: "memory"); \
                     __builtin_amdgcn_sched_barrier(0); } while (0)
#define WAIT0() do { asm volatile("s_waitcnt lgkmcnt(0)" ::: "memory"); \
                     __builtin_amdgcn_sched_barrier(0); } while (0)

    uint4 q0a = pko[0], q0b = pko[1];
    uint4 q1a = pko[2], q1b = pko[3];
    uint4 q2a = pko[4], q2b = pko[5];
    uint4 q3a = pko[6], q3b = pko[7];

    v4u vA0, vA1, vA2, vA3, vB0, vB1, vB2, vB3;
    uint32_t wA0, wA1, wA2, wA3, wB0, wB1, wB2, wB3;

    DSREAD(vA0, q0a.x); DSREAD(vA1, q0a.z); DSREAD(vA2, q0b.x); DSREAD(vA3, q0b.z);
    wA0 = q0a.y; wA1 = q0a.w; wA2 = q0b.y; wA3 = q0b.w;

#define STEP(Cc, QI0, QI1, QR0, QR1,                                   \
             VC0, VC1, VC2, VC3, WC0, WC1, WC2, WC3,                   \
             VI0, VI1, VI2, VI3, WI0, WI1, WI2, WI3)                   \
  do {                                                                 \
    DSREAD(VI0, QI0.x); DSREAD(VI1, QI0.z);                            \
    DSREAD(VI2, QI1.x); DSREAD(VI3, QI1.z);                            \
    WI0 = QI0.y; WI1 = QI0.w; WI2 = QI1.y; WI3 = QI1.w;                \
    {                                                                  \
      const int gn_ = ((Cc) + 4 > 31) ? 31 : ((Cc) + 4);               \
      QR0 = pko[2 * gn_];                                              \
      QR1 = pko[2 * gn_ + 1];                                          \
    }                                                                  \
    WAIT4();                                                           \
    CONSUME(VC0, WC0); CONSUME(VC1, WC1);                              \
    CONSUME(VC2, WC2); CONSUME(VC3, WC3);                              \
  } while (0)
#define STEP_A(Cc, QI0, QI1, QR0, QR1)                                   \
  STEP(Cc, QI0, QI1, QR0, QR1,                                           \
       vA0, vA1, vA2, vA3, wA0, wA1, wA2, wA3,                           \
       vB0, vB1, vB2, vB3, wB0, wB1, wB2, wB3)
#define STEP_B(Cc, QI0, QI1, QR0, QR1)                                   \
  STEP(Cc, QI0, QI1, QR0, QR1,                                           \
       vB0, vB1, vB2, vB3, wB0, wB1, wB2, wB3,                           \
       vA0, vA1, vA2, vA3, wA0, wA1, wA2, wA3)

#pragma unroll 1
    for (int cb = 0; cb < 28; cb += 4) {
      STEP_A(cb + 0, q1a, q1b, q0a, q0b);
      STEP_B(cb + 1, q2a, q2b, q1a, q1b);
      STEP_A(cb + 2, q3a, q3b, q2a, q2b);
      STEP_B(cb + 3, q0a, q0b, q3a, q3b);
    }
    STEP_A(28, q1a, q1b, q0a, q0b);
    STEP_B(29, q2a, q2b, q1a, q1b);
    STEP_A(30, q3a, q3b, q2a, q2b);
    WAIT0();
    CONSUME(vB0, wB0); CONSUME(vB1, wB1); CONSUME(vB2, wB2); CONSUME(vB3, wB3);
#undef STEP_B
#undef STEP_A
#undef STEP
#undef WAIT4
#undef WAIT0
#undef DSREAD

    const float bz = bias[o];
    const float r[8] = {a0[0], a0[1], a1[0], a1[1], a2[0], a2[1], a3[0], a3[1]};
    const size_t obase = (size_t)(bg * BCHUNK + p * 8) * OUT_F + o;
#pragma unroll
    for (int i = 0; i < 8; ++i) out[obase + (size_t)i * OUT_F] = r[i] + bz;

  } else {
    // =================== L2 leg (R10 pipeline) =============================
    const int o = __builtin_amdgcn_readfirstlane(O_SPLIT + blk * 8 + (wv - 8));
    const int*   __restrict__ idxo = idx + (size_t)o * FAN_IN;
    const float* __restrict__ wo   = weight + (size_t)o * FAN_IN;
    const uint32_t voff = (uint32_t)l * 16u;

#define GISSUE(S, jj)                                                        \
  do {                                                                       \
    const uint32_t va_ = ((uint32_t)(jj) << 10) + voff;                      \
    asm volatile("global_load_dwordx4 %0, %1, %2"                            \
                 : "=&v"(S) : "v"(va_), "s"(inTf));                          \
  } while (0)
#define WAITV(n) do { asm volatile("s_waitcnt vmcnt(" #n ")" ::: "memory");  \
                      __builtin_amdgcn_sched_barrier(0); } while (0)

    v4u S0, S1, S2, S3;
    int   j0 = idxo[0], j1 = idxo[1], j2 = idxo[2], j3 = idxo[3];
    float w0 = wo[0],   w1 = wo[1],   w2 = wo[2],   w3 = wo[3];

    GISSUE(S0, j0); GISSUE(S1, j1); GISSUE(S2, j2); GISSUE(S3, j3);

#pragma unroll 1
    for (int c = 0; c < 124; c += 4) {
      const int   jn0 = idxo[c + 4], jn1 = idxo[c + 5];
      const int   jn2 = idxo[c + 6], jn3 = idxo[c + 7];
      const float wn0 = wo[c + 4],   wn1 = wo[c + 5];
      const float wn2 = wo[c + 6],   wn3 = wo[c + 7];
      WAITV(3); CONSUME(S0, __float_as_uint(w0)); GISSUE(S0, jn0); w0 = wn0;
      WAITV(3); CONSUME(S1, __float_as_uint(w1)); GISSUE(S1, jn1); w1 = wn1;
      WAITV(3); CONSUME(S2, __float_as_uint(w2)); GISSUE(S2, jn2); w2 = wn2;
      WAITV(3); CONSUME(S3, __float_as_uint(w3)); GISSUE(S3, jn3); w3 = wn3;
    }
    WAITV(3); CONSUME(S0, __float_as_uint(w0));
    WAITV(2); CONSUME(S1, __float_as_uint(w1));
    WAITV(1); CONSUME(S2, __float_as_uint(w2));
    WAITV(0); CONSUME(S3, __float_as_uint(w3));
#undef WAITV
#undef GISSUE

    const float bz = bias[o];
    float4 r0 = make_float4(a0[0] + bz, a0[1] + bz, a1[0] + bz, a1[1] + bz);
    float4 r1 = make_float4(a2[0] + bz, a2[1] + bz, a3[0] + bz, a3[1] + bz);
    float4* dst =
        reinterpret_cast<float4*>(outT + (size_t)(o - O_SPLIT) * BATCH + l * 8);
    dst[0] = r0;
    dst[1] = r1;
  }
}

// ---------------------------------------------------------------------------
// Kernel C: partial transpose — outT rows [0,2048) = o in [2048,4096)
//   out[b][2048+oo] = outT[oo][b]
// ---------------------------------------------------------------------------
__global__ __launch_bounds__(256) void k_transpose_out(const float* __restrict__ outT,
                                                       float* __restrict__ out) {
  __shared__ float tile[32][33];
  const int ot = blockIdx.x * 32;   // oo tile (0..2047)
  const int bt = blockIdx.y * 32;
  const int tx = threadIdx.x;
  const int ty = threadIdx.y;
#pragma unroll
  for (int r = 0; r < 32; r += 8) {
    tile[ty + r][tx] = outT[(size_t)(ot + ty + r) * BATCH + (bt + tx)];
  }
  __syncthreads();
#pragma unroll
  for (int r = 0; r < 32; r += 8) {
    out[(size_t)(bt + ty + r) * OUT_F + (O_SPLIT + ot + tx)] = tile[tx][ty + r];
  }
}

extern "C" void kernel_launch(void* const* d_in, const int* in_sizes, int n_in,
                              void* d_out, int out_size, void* d_ws, size_t ws_size,
                              hipStream_t stream) {
  const float* input  = (const float*)d_in[0];   // [512][4096] f32
  const float* weight = (const float*)d_in[1];   // [4096][128] f32
  const float* bias   = (const float*)d_in[2];   // [4096]      f32
  const int*   idx    = (const int*)d_in[3];     // [4096][128] int32
  float* out = (float*)d_out;                    // [512][4096] f32

  // ws: inTg 4MB | inTf 4MB | pk 2MB (o<2048) | outT 4MB (o>=2048)
  uint16_t* inTg = (uint16_t*)d_ws;
  uint16_t* inTf = (uint16_t*)((char*)d_ws + 4u * 1024 * 1024);
  uint2*    pk   = (uint2*)((char*)d_ws + 8u * 1024 * 1024);
  float*    outT = (float*)((char*)d_ws + 10u * 1024 * 1024);

  dim3 tblk(32, 8);
  k_transpose_in<<<dim3(IN_WIDTH / 32, BATCH / 32), tblk, 0, stream>>>(input, inTg, inTf);
  k_pack<<<dim3(O_SPLIT * FAN_IN / 256), dim3(256), 0, stream>>>(idx, weight, pk);
  k_gather_hyb2<<<dim3(8 * NBG), dim3(1024), IN_WIDTH * BCHUNK * 2, stream>>>(
      inTg, inTf, pk, idx, weight, bias, out, outT);
  k_transpose_out<<<dim3(O_SPLIT / 32, BATCH / 32), tblk, 0, stream>>>(outT, out);
}

// Round 13
// 35.889 us; speedup vs baseline: 1.2143x; 1.2143x over previous
//
#include <hip/hip_runtime.h>
#include <hip/hip_bf16.h>

#define BATCH    512
#define IN_WIDTH 4096
#define OUT_F    4096
#define FAN_IN   128
#define BCHUNK   16                 // batches per LDS-resident slice
#define NBG      (BATCH / BCHUNK)   // 32
#define OBLK     512                // o-range per gather block
#define NOG      (OUT_F / OBLK)     // 8

typedef float    v2f __attribute__((ext_vector_type(2)));
typedef uint32_t v4u __attribute__((ext_vector_type(4)));

// ---------------------------------------------------------------------------
// Kernel A+P fused: blocks [0,2048): transpose input[b][j] f32 ->
// inTg[b/16][j][16] bf16 (chunk-major). Blocks [2048,4096): pack idx+weight
// -> pk[o][f] = {j, bits(w)}.
// ---------------------------------------------------------------------------
__global__ __launch_bounds__(256) void k_prep(const float* __restrict__ in,
                                              const int* __restrict__ idx,
                                              const float* __restrict__ weight,
                                              uint16_t* __restrict__ inTg,
                                              uint2* __restrict__ pk) {
  __shared__ float tile[32][33];
  const int blk = blockIdx.x;
  const int t   = threadIdx.x;
  if (blk < 2048) {
    // ---- transpose section: blk -> (jt = (blk&127)*32, bt = (blk>>7)*32)
    const int jt = (blk & 127) * 32;
    const int bt = (blk >> 7) * 32;
    const int tx = t & 31;          // j_local
    const int ty = t >> 5;          // 0..7
#pragma unroll
    for (int r = 0; r < 32; r += 8) {
      tile[ty + r][tx] = in[(size_t)(bt + ty + r) * IN_WIDTH + (jt + tx)];
    }
    __syncthreads();
#pragma unroll
    for (int r = 0; r < 32; r += 8) {
      const int b = bt + tx;
      const int j = jt + ty + r;
      __hip_bfloat16 hv = __float2bfloat16(tile[tx][ty + r]);
      inTg[((size_t)(b >> 4) * IN_WIDTH + j) * BCHUNK + (b & 15)] =
          *reinterpret_cast<const uint16_t*>(&hv);
    }
  } else {
    // ---- pack section
    const int i = (blk - 2048) * 256 + t;       // 0 .. 524287
    uint2 e;
    e.x = (uint32_t)idx[i];
    e.y = __float_as_uint(weight[i]);
    pk[i] = e;
  }
}

// ---------------------------------------------------------------------------
// Kernel B: LDS-staged gather (R7 structure, unchanged pipeline).
// Staging via __builtin_amdgcn_global_load_lds width=16: per-lane GLOBAL
// address, wave-uniform LDS dest (base + lane*16) — slice bytes skip the
// VGPR return path. DS depth-4 pipeline w/ counted lgkmcnt(4); 4-slot
// rotating pk prefetch.
// ---------------------------------------------------------------------------
__global__ __launch_bounds__(1024, 4) void k_gather_lds(const uint16_t* __restrict__ inTg,
                                                        const uint2* __restrict__ pk,
                                                        const float* __restrict__ bias,
                                                        float* __restrict__ out) {
  extern __shared__ char lds[];
  const int og = blockIdx.x;
  const int bg = blockIdx.y;
  const int t  = threadIdx.x;

  // ---- stage 128 KB via direct global->LDS (no VGPR round trip) ----
  {
    const v4u* __restrict__ src =
        reinterpret_cast<const v4u*>(inTg + (size_t)bg * IN_WIDTH * BCHUNK);
#pragma unroll
    for (int i = 0; i < 8; ++i) {
      const v4u* g = src + i * 1024 + t;                     // per-lane global
      char* d = lds + ((t >> 6) << 10) + (i << 14);          // wave-uniform + lane*16
      __builtin_amdgcn_global_load_lds(
          (const __attribute__((address_space(1))) void*)g,
          (__attribute__((address_space(3))) void*)d, 16, 0, 0);
    }
    asm volatile("s_waitcnt vmcnt(0)" ::: "memory");
  }
  __syncthreads();

  const int wv = t >> 6;
  const int l  = t & 63;
  const int o  = og * OBLK + wv * 32 + (l >> 1);  // 32 o per wave, 2 lanes/o
  const int p  = l & 1;                           // batch half (8 of 16)

  const uint32_t sb = (uint32_t)(size_t)lds + (uint32_t)(p * 16);

  const uint4* __restrict__ pko =
      reinterpret_cast<const uint4*>(pk + (size_t)o * FAN_IN);   // 64 entries

  v2f a0 = {0.f, 0.f}, a1 = {0.f, 0.f}, a2 = {0.f, 0.f}, a3 = {0.f, 0.f};

#define DSREAD(d, jj) \
  asm volatile("ds_read_b128 %0, %1" : "=v"(d) : "v"(sb + ((jj) << 5)))

#define WAIT4() do { asm volatile("s_waitcnt lgkmcnt(4)" ::: "memory"); \
                     __builtin_amdgcn_sched_barrier(0); } while (0)
#define WAIT0() do { asm volatile("s_waitcnt lgkmcnt(0)" ::: "memory"); \
                     __builtin_amdgcn_sched_barrier(0); } while (0)

#define CONSUME(v, wbits)                                              \
  do {                                                                 \
    const float wf_ = __uint_as_float(wbits);                          \
    v2f w2_; w2_[0] = wf_; w2_[1] = wf_;                               \
    v2f x0_, x1_, x2_, x3_;                                            \
    x0_[0] = __uint_as_float((v)[0] << 16);                            \
    x0_[1] = __uint_as_float((v)[0] & 0xffff0000u);                    \
    x1_[0] = __uint_as_float((v)[1] << 16);                            \
    x1_[1] = __uint_as_float((v)[1] & 0xffff0000u);                    \
    x2_[0] = __uint_as_float((v)[2] << 16);                            \
    x2_[1] = __uint_as_float((v)[2] & 0xffff0000u);                    \
    x3_[0] = __uint_as_float((v)[3] << 16);                            \
    x3_[1] = __uint_as_float((v)[3] & 0xffff0000u);                    \
    a0 += x0_ * w2_; a1 += x1_ * w2_; a2 += x2_ * w2_; a3 += x3_ * w2_;\
  } while (0)

  // q slots: slot s holds pk group g with g%4==s; refill slot c%4 with
  // group c+4 at iteration c (w's copied out at issue time).
  uint4 q0a = pko[0], q0b = pko[1];   // g0
  uint4 q1a = pko[2], q1b = pko[3];   // g1
  uint4 q2a = pko[4], q2b = pko[5];   // g2
  uint4 q3a = pko[6], q3b = pko[7];   // g3

  v4u vA0, vA1, vA2, vA3, vB0, vB1, vB2, vB3;
  uint32_t wA0, wA1, wA2, wA3, wB0, wB1, wB2, wB3;

  DSREAD(vA0, q0a.x); DSREAD(vA1, q0a.z); DSREAD(vA2, q0b.x); DSREAD(vA3, q0b.z);
  wA0 = q0a.y; wA1 = q0a.w; wA2 = q0b.y; wA3 = q0b.w;

#define STEP(Cc, QI0, QI1, QR0, QR1,                                   \
             VC0, VC1, VC2, VC3, WC0, WC1, WC2, WC3,                   \
             VI0, VI1, VI2, VI3, WI0, WI1, WI2, WI3)                   \
  do {                                                                 \
    DSREAD(VI0, QI0.x); DSREAD(VI1, QI0.z);                            \
    DSREAD(VI2, QI1.x); DSREAD(VI3, QI1.z);                            \
    WI0 = QI0.y; WI1 = QI0.w; WI2 = QI1.y; WI3 = QI1.w;                \
    {                                                                  \
      const int gn_ = ((Cc) + 4 > 31) ? 31 : ((Cc) + 4);               \
      QR0 = pko[2 * gn_];                                              \
      QR1 = pko[2 * gn_ + 1];                                          \
    }                                                                  \
    WAIT4();                                                           \
    CONSUME(VC0, WC0); CONSUME(VC1, WC1);                              \
    CONSUME(VC2, WC2); CONSUME(VC3, WC3);                              \
  } while (0)

#define STEP_A(Cc, QI0, QI1, QR0, QR1)                                   \
  STEP(Cc, QI0, QI1, QR0, QR1,                                           \
       vA0, vA1, vA2, vA3, wA0, wA1, wA2, wA3,                           \
       vB0, vB1, vB2, vB3, wB0, wB1, wB2, wB3)
#define STEP_B(Cc, QI0, QI1, QR0, QR1)                                   \
  STEP(Cc, QI0, QI1, QR0, QR1,                                           \
       vB0, vB1, vB2, vB3, wB0, wB1, wB2, wB3,                           \
       vA0, vA1, vA2, vA3, wA0, wA1, wA2, wA3)

#pragma unroll 1
  for (int cb = 0; cb < 28; cb += 4) {
    STEP_A(cb + 0, q1a, q1b, q0a, q0b);
    STEP_B(cb + 1, q2a, q2b, q1a, q1b);
    STEP_A(cb + 2, q3a, q3b, q2a, q2b);
    STEP_B(cb + 3, q0a, q0b, q3a, q3b);
  }
  STEP_A(28, q1a, q1b, q0a, q0b);
  STEP_B(29, q2a, q2b, q1a, q1b);
  STEP_A(30, q3a, q3b, q2a, q2b);
  // after c=30: A consumed g30, B holds g31 in flight
  WAIT0();
  CONSUME(vB0, wB0); CONSUME(vB1, wB1); CONSUME(vB2, wB2); CONSUME(vB3, wB3);

  const float bz = bias[o];
  const float r[8] = {a0[0], a0[1], a1[0], a1[1], a2[0], a2[1], a3[0], a3[1]};
  // out[b][o], b = bg*16 + p*8 + i ; per store a wave covers 2 x 128 B rows
  const size_t obase = (size_t)(bg * BCHUNK + p * 8) * OUT_F + o;
#pragma unroll
  for (int i = 0; i < 8; ++i) out[obase + (size_t)i * OUT_F] = r[i] + bz;

#undef STEP_B
#undef STEP_A
#undef STEP
#undef CONSUME
#undef WAIT4
#undef WAIT0
#undef DSREAD
}

extern "C" void kernel_launch(void* const* d_in, const int* in_sizes, int n_in,
                              void* d_out, int out_size, void* d_ws, size_t ws_size,
                              hipStream_t stream) {
  const float* input  = (const float*)d_in[0];   // [512][4096] f32
  const float* weight = (const float*)d_in[1];   // [4096][128] f32
  const float* bias   = (const float*)d_in[2];   // [4096]      f32
  const int*   idx    = (const int*)d_in[3];     // [4096][128] int32
  float* out = (float*)d_out;                    // [512][4096] f32

  // ws: inTg (bf16, 4 MB) | pk (uint2, 4 MB)
  uint16_t* inTg = (uint16_t*)d_ws;
  uint2*    pk   = (uint2*)((char*)d_ws + 4u * 1024 * 1024);

  k_prep<<<dim3(4096), dim3(256), 0, stream>>>(input, idx, weight, inTg, pk);
  k_gather_lds<<<dim3(NOG, NBG), dim3(1024), IN_WIDTH * BCHUNK * 2, stream>>>(
      inTg, pk, bias, out);
}